// Round 3
// baseline (124.595 us; speedup 1.0000x reference)
//
#include <hip/hip_runtime.h>

// CALayer: the reference applies LayerNorm over a singleton axis ([B,6,1],
// axis=-1). mean(x) over a size-1 axis == x exactly, so (out-mu)==0 and
// var==0 exactly; the result is 0/sqrt(1e-5)*ln_g + ln_b == ln_b broadcast.
// The entire upstream graph (co-attention, cross-attentions, projections) is
// unobservable at the output. Exact-optimal kernel: broadcast ln_b[0] into
// all out_size floats.

__global__ void calayer_broadcast_lnb(const float* __restrict__ ln_b,
                                      float* __restrict__ out, int n) {
    const float v = ln_b[0];               // == 0.0f per setup_inputs; broadcast L1-hit
    const int i = blockIdx.x * blockDim.x + threadIdx.x;
    const int i4 = i * 4;
    if (i4 + 3 < n) {
        // coalesced 16B stores: 49152 floats -> 12288 lanes
        *reinterpret_cast<float4*>(out + i4) = make_float4(v, v, v, v);
    } else {
        // tail guard (out_size % 4 == 0 for this problem, but stay safe)
        for (int k = i4; k < n; ++k) out[k] = v;
    }
}

extern "C" void kernel_launch(void* const* d_in, const int* in_sizes, int n_in,
                              void* d_out, int out_size, void* d_ws, size_t ws_size,
                              hipStream_t stream) {
    (void)in_sizes; (void)d_ws; (void)ws_size;
    const float* ln_b = (const float*)d_in[n_in - 1];   // ln_b is the last input
    float* out = (float*)d_out;

    const int n4 = (out_size + 3) / 4;                  // lanes, 4 floats each
    const int block = 256;
    const int grid = (n4 + block - 1) / block;          // 48 blocks for 49152 floats
    calayer_broadcast_lnb<<<grid, block, 0, stream>>>(ln_b, out, out_size);
}